// Round 14
// baseline (623.154 us; speedup 1.0000x reference)
//
#include <hip/hip_runtime.h>
#include <math.h>

// ===========================================================================
// EnergyGCN round 13:
// (a) GEMM: full-prefetch into named register arrays (fixes r12 finding:
//     VGPR=32 register-throttled serial loads). All A+B fragment loads issued
//     before MFMAs; K>128 split into 2 halves to bound reg pressure.
// (b) SpMM: 4 column-slab passes (32 cols = 64B/row each, 3.2MB footprint
//     fits per-XCD 4MB L2). Fixes r12 finding: gather is L3-BW-bound, not
//     latency-bound. pass = blockIdx.x / nb4, 8 edges/round via oct lanes.
// Numerics identical to round 10/12 (bf16 h/h0/pre, fp32 out).
// ===========================================================================

typedef __bf16 bf16x8 __attribute__((ext_vector_type(8)));
typedef float f32x4 __attribute__((ext_vector_type(4)));
typedef unsigned int uint32x4 __attribute__((ext_vector_type(4)));

__device__ __forceinline__ ushort f2bf(float f) {  // RNE float->bf16
  unsigned u = __float_as_uint(f);
  return (ushort)((u + 0x7fffu + ((u >> 16) & 1u)) >> 16);
}
__device__ __forceinline__ float bflo(unsigned u) { return __uint_as_float(u << 16); }
__device__ __forceinline__ float bfhi(unsigned u) { return __uint_as_float(u & 0xffff0000u); }

// ---------------- CSR build ----------------
__global__ void k_count(const int* __restrict__ eidx, int* __restrict__ degi, int E, int n) {
  int e = blockIdx.x * blockDim.x + threadIdx.x;
  if (e < E) {
    int r = eidx[e];
    if ((unsigned)r < (unsigned)n) atomicAdd(&degi[r], 1);
  }
}

__global__ __launch_bounds__(1024) void k_scan1(const int* __restrict__ degi,
                                                int* __restrict__ rowstart,
                                                int* __restrict__ bsum, int n) {
  __shared__ int sm[1024];
  int tid = threadIdx.x;
  int i = blockIdx.x * 1024 + tid;
  int v = (i < n) ? degi[i] : 0;
  sm[tid] = v;
  __syncthreads();
  #pragma unroll
  for (int off = 1; off < 1024; off <<= 1) {
    int t = (tid >= off) ? sm[tid - off] : 0;
    __syncthreads();
    sm[tid] += t;
    __syncthreads();
  }
  if (i < n) rowstart[i] = sm[tid] - v;
  if (tid == 1023) bsum[blockIdx.x] = sm[1023];
}

__global__ void k_scan2(const int* __restrict__ bsum, int* __restrict__ boff, int nb) {
  if (threadIdx.x == 0 && blockIdx.x == 0) {
    int s = 0;
    for (int b = 0; b < nb; ++b) { boff[b] = s; s += bsum[b]; }
  }
}

__global__ __launch_bounds__(1024) void k_scan3(int* __restrict__ rowstart,
                                                const int* __restrict__ boff,
                                                int* __restrict__ cursor,
                                                const int* __restrict__ degi,
                                                float* __restrict__ dinv, int n, int E) {
  int i = blockIdx.x * 1024 + threadIdx.x;
  if (i < n) {
    int v = rowstart[i] + boff[blockIdx.x];
    rowstart[i] = v;
    cursor[i] = v;
    dinv[i] = rsqrtf((float)degi[i] + 1.0f);  // +1 = self loop
  }
  if (i == 0) rowstart[n] = E;
}

template <typename IDX>
__global__ void k_fill(const int* __restrict__ eidx, int* __restrict__ cursor,
                       IDX* __restrict__ colidx, int E, int n) {
  int e = blockIdx.x * blockDim.x + threadIdx.x;
  if (e < E) {
    int r = eidx[e];
    int c = eidx[E + e];
    if ((unsigned)r < (unsigned)n && (unsigned)c < (unsigned)n) {
      int pos = atomicAdd(&cursor[r], 1);
      colidx[pos] = (IDX)c;
    }
  }
}

// ---------------- weight convert/transpose to bf16 [j][k] ----------------
__global__ void k_cvt(const float* __restrict__ Wr, const float* __restrict__ W1,
                      const float* __restrict__ W2, ushort* __restrict__ wr_bf,
                      ushort* __restrict__ w1t, ushort* __restrict__ w2t,
                      int nwr, int nw1, int nw2) {
  int i = blockIdx.x * blockDim.x + threadIdx.x;
  if (i < nwr) {
    wr_bf[i] = f2bf(Wr[i]);
  } else if (i < nwr + nw1) {
    int m = i - nwr;             // m = k*128 + j  (W1 is [256][128])
    int k = m >> 7, j = m & 127;
    w1t[j * 256 + k] = f2bf(W1[m]);
  } else if (i < nwr + nw1 + nw2) {
    int m = i - nwr - nw1;       // m = k*64 + j   (W2 is [128][64])
    int k = m >> 6, j = m & 63;
    w2t[j * 128 + k] = f2bf(W2[m]);
  }
}

// ---------------- MFMA GEMM: C[n,NOUT] = A[n,K] @ Bt^T ----------------
// Full-prefetch: all A+B fragments of a K-half loaded into named register
// arrays (static indices, fully unrolled) BEFORE the MFMA cluster, so the
// compiler must co-issue the loads (r12: VGPR=32 serialization bug).
// K<=128: one half. K=256: two halves of 128.
template <int K, int NOUT, int CW, bool AF32, int EPI>
__global__ __launch_bounds__(256) void mfma_gemm(const void* __restrict__ Ap,
                                                 const ushort* __restrict__ Bt,
                                                 const float* __restrict__ bias,
                                                 const float* __restrict__ dinv,
                                                 ushort* __restrict__ out_bf,
                                                 float* __restrict__ out_f32,
                                                 int n) {
  constexpr int KH = (K > 128) ? 2 : 1;   // K halves
  constexpr int KSH = K / 32 / KH;        // kk-steps per half (4)
  constexpr int NT = NOUT / 16 / CW;      // col-tiles per wave
  constexpr int ROWS = (4 / CW) * 16;     // rows per block
  const int lane = threadIdx.x & 63;
  const int wave = threadIdx.x >> 6;
  const int rw = wave / CW;
  const int cw = wave % CW;
  const int l15 = lane & 15;
  const int kq = lane >> 4;
  const int col0 = cw * (NOUT / CW);
  const int rowA = blockIdx.x * ROWS + rw * 16 + l15;
  const bool arow_ok = rowA < n;

  f32x4 acc[NT];
  #pragma unroll
  for (int t = 0; t < NT; ++t) acc[t] = (f32x4){0.f, 0.f, 0.f, 0.f};

  #pragma unroll
  for (int h = 0; h < KH; ++h) {
    const int kbase = h * 128;
    // ---- issue ALL A loads for this half ----
    uint32x4 areg[KSH];
    if constexpr (AF32) {
      const float* A = (const float*)Ap;
      float4 f0[KSH], f1[KSH];
      #pragma unroll
      for (int kk = 0; kk < KSH; ++kk) {
        f0[kk] = make_float4(0.f, 0.f, 0.f, 0.f);
        f1[kk] = make_float4(0.f, 0.f, 0.f, 0.f);
        if (arow_ok) {
          f0[kk] = *(const float4*)&A[(size_t)rowA * K + kbase + kk * 32 + kq * 8];
          f1[kk] = *(const float4*)&A[(size_t)rowA * K + kbase + kk * 32 + kq * 8 + 4];
        }
      }
      // ---- issue ALL B loads ----
      uint32x4 breg[KSH][NT];
      #pragma unroll
      for (int kk = 0; kk < KSH; ++kk)
        #pragma unroll
        for (int t = 0; t < NT; ++t)
          breg[kk][t] = *(const uint32x4*)&Bt[(size_t)(col0 + t * 16 + l15) * K +
                                              kbase + kk * 32 + kq * 8];
      // ---- convert A, then MFMA cluster ----
      #pragma unroll
      for (int kk = 0; kk < KSH; ++kk) {
        uint32x4 u;
        u[0] = (unsigned)f2bf(f0[kk].x) | ((unsigned)f2bf(f0[kk].y) << 16);
        u[1] = (unsigned)f2bf(f0[kk].z) | ((unsigned)f2bf(f0[kk].w) << 16);
        u[2] = (unsigned)f2bf(f1[kk].x) | ((unsigned)f2bf(f1[kk].y) << 16);
        u[3] = (unsigned)f2bf(f1[kk].z) | ((unsigned)f2bf(f1[kk].w) << 16);
        areg[kk] = u;
      }
      #pragma unroll
      for (int kk = 0; kk < KSH; ++kk) {
        bf16x8 a = __builtin_bit_cast(bf16x8, areg[kk]);
        #pragma unroll
        for (int t = 0; t < NT; ++t) {
          bf16x8 b = __builtin_bit_cast(bf16x8, breg[kk][t]);
          acc[t] = __builtin_amdgcn_mfma_f32_16x16x32_bf16(a, b, acc[t], 0, 0, 0);
        }
      }
    } else {
      const ushort* A = (const ushort*)Ap;
      #pragma unroll
      for (int kk = 0; kk < KSH; ++kk) {
        areg[kk] = (uint32x4){0u, 0u, 0u, 0u};
        if (arow_ok)
          areg[kk] = *(const uint32x4*)&A[(size_t)rowA * K + kbase + kk * 32 + kq * 8];
      }
      uint32x4 breg[KSH][NT];
      #pragma unroll
      for (int kk = 0; kk < KSH; ++kk)
        #pragma unroll
        for (int t = 0; t < NT; ++t)
          breg[kk][t] = *(const uint32x4*)&Bt[(size_t)(col0 + t * 16 + l15) * K +
                                              kbase + kk * 32 + kq * 8];
      #pragma unroll
      for (int kk = 0; kk < KSH; ++kk) {
        bf16x8 a = __builtin_bit_cast(bf16x8, areg[kk]);
        #pragma unroll
        for (int t = 0; t < NT; ++t) {
          bf16x8 b = __builtin_bit_cast(bf16x8, breg[kk][t]);
          acc[t] = __builtin_amdgcn_mfma_f32_16x16x32_bf16(a, b, acc[t], 0, 0, 0);
        }
      }
    }
  }

  const int rbase = blockIdx.x * ROWS + rw * 16 + kq * 4;  // C/D rows

  float bcol[NT];
  #pragma unroll
  for (int t = 0; t < NT; ++t) {
    if constexpr (EPI != 1) bcol[t] = bias[col0 + t * 16 + l15];
    else bcol[t] = 0.f;
  }
  float sc[4];
  #pragma unroll
  for (int r = 0; r < 4; ++r) {
    if constexpr (EPI == 1) sc[r] = (rbase + r < n) ? dinv[rbase + r] : 0.f;
    else sc[r] = 0.f;
  }

  #pragma unroll
  for (int r = 0; r < 4; ++r) {
    int row = rbase + r;
    if (row < n) {
      #pragma unroll
      for (int t = 0; t < NT; ++t) {
        int col = col0 + t * 16 + l15;
        float v = acc[t][r];
        if constexpr (EPI == 0) {
          v += bcol[t];
          v = fmaxf(v, 0.f);
          out_bf[(size_t)row * NOUT + col] = f2bf(v);
        } else if constexpr (EPI == 1) {
          out_bf[(size_t)row * NOUT + col] = f2bf(v * sc[r]);
        } else {
          out_f32[(size_t)row * NOUT + col] = v + bcol[t];
        }
      }
    }
  }
}

// ---------------- fused SpMM + residual, column-slab passes ----------------
// grid = 4 * nb4; pass = bid / nb4 selects 32-col slab (64B/row -> 3.2MB
// footprint, fits per-XCD L2). lane = oct*8 + c8: oct owns edge slot 8i+oct,
// c8 owns 4 cols (8B). Reduce xor 8/16/32; oct 0 writes.
template <typename IDX>
__global__ __launch_bounds__(256) void k_spmm5(const ushort* __restrict__ pre,
                                               const float* __restrict__ dinv,
                                               const int* __restrict__ rowstart,
                                               const IDX* __restrict__ colidx,
                                               const float* __restrict__ eps, int layer,
                                               const ushort* __restrict__ h0in,
                                               ushort* __restrict__ h0out,
                                               ushort* __restrict__ hbf, int n) {
  const int nb4 = gridDim.x >> 2;
  const int pass = blockIdx.x / nb4;
  const int bid = blockIdx.x - pass * nb4;
  const int lane = threadIdx.x & 63;
  const int r = bid * 4 + (threadIdx.x >> 6);
  if (r >= n) return;

  const int s0 = rowstart[r], s1 = rowstart[r + 1];
  const float dr = dinv[r];
  const int oct = lane >> 3;         // edge slot
  const int c8 = lane & 7;           // 4-col group within slab
  const int slab = pass * 32;
  const size_t rowb = (size_t)r * 128 + slab + c8 * 4;

  const uint2 pr = *(const uint2*)&pre[rowb];
  const uint2 h0u = *(const uint2*)&h0in[rowb];

  float a0 = 0.f, a1 = 0.f, a2 = 0.f, a3 = 0.f;

  for (int base = s0; base < s1; base += 64) {
    int m = s1 - base; if (m > 64) m = 64;
    int ci = 0;
    if (base + lane < s1) ci = (int)colidx[base + lane];
    int full8 = m >> 3;
    int i = 0;
    for (; i + 1 < full8; i += 2) {  // 16 edges, 2 loads in flight/lane
      int cA = __shfl(ci, 8 * i + oct);
      int cB = __shfl(ci, 8 * i + 8 + oct);
      uint2 uA = *(const uint2*)&pre[(size_t)cA * 128 + slab + c8 * 4];
      uint2 uB = *(const uint2*)&pre[(size_t)cB * 128 + slab + c8 * 4];
      a0 += bflo(uA.x); a1 += bfhi(uA.x); a2 += bflo(uA.y); a3 += bfhi(uA.y);
      a0 += bflo(uB.x); a1 += bfhi(uB.x); a2 += bflo(uB.y); a3 += bfhi(uB.y);
    }
    for (; i < full8; ++i) {
      int cA = __shfl(ci, 8 * i + oct);
      uint2 uA = *(const uint2*)&pre[(size_t)cA * 128 + slab + c8 * 4];
      a0 += bflo(uA.x); a1 += bfhi(uA.x); a2 += bflo(uA.y); a3 += bfhi(uA.y);
    }
    int rem = m & 7;                 // tail: octs < rem take one edge
    if (rem) {
      int cZ = __shfl(ci, full8 * 8 + (oct < rem ? oct : 0));
      if (oct < rem) {
        uint2 uZ = *(const uint2*)&pre[(size_t)cZ * 128 + slab + c8 * 4];
        a0 += bflo(uZ.x); a1 += bfhi(uZ.x); a2 += bflo(uZ.y); a3 += bfhi(uZ.y);
      }
    }
  }
  a0 += __shfl_xor(a0, 8);  a1 += __shfl_xor(a1, 8);
  a2 += __shfl_xor(a2, 8);  a3 += __shfl_xor(a3, 8);
  a0 += __shfl_xor(a0, 16); a1 += __shfl_xor(a1, 16);
  a2 += __shfl_xor(a2, 16); a3 += __shfl_xor(a3, 16);
  a0 += __shfl_xor(a0, 32); a1 += __shfl_xor(a1, 32);
  a2 += __shfl_xor(a2, 32); a3 += __shfl_xor(a3, 32);

  if (oct == 0) {
    const float aa = (6.0f - 3.0f * dr * dr) / dr;
    const float m3 = -3.0f * dr;
    const float g = 1.0f + tanhf(eps[layer]);
    float v0 = g * bflo(h0u.x) + aa * bflo(pr.x) + m3 * a0;
    float v1 = g * bfhi(h0u.x) + aa * bfhi(pr.x) + m3 * a1;
    float v2 = g * bflo(h0u.y) + aa * bflo(pr.y) + m3 * a2;
    float v3 = g * bfhi(h0u.y) + aa * bfhi(pr.y) + m3 * a3;
    uint2 ho, hr;
    ho.x = (unsigned)f2bf(v0) | ((unsigned)f2bf(v1) << 16);
    ho.y = (unsigned)f2bf(v2) | ((unsigned)f2bf(v3) << 16);
    hr.x = (unsigned)f2bf(fmaxf(v0, 0.f)) | ((unsigned)f2bf(fmaxf(v1, 0.f)) << 16);
    hr.y = (unsigned)f2bf(fmaxf(v2, 0.f)) | ((unsigned)f2bf(fmaxf(v3, 0.f)) << 16);
    *(uint2*)&h0out[rowb] = ho;
    *(uint2*)&hbf[rowb] = hr;
  }
}

// ---------------- launch ----------------
extern "C" void kernel_launch(void* const* d_in, const int* in_sizes, int n_in,
                              void* d_out, int out_size, void* d_ws, size_t ws_size,
                              hipStream_t stream) {
  const float* x   = (const float*)d_in[0];
  const float* W1  = (const float*)d_in[1];
  const float* b1  = (const float*)d_in[2];
  const float* Wr  = (const float*)d_in[3];
  const float* eps = (const float*)d_in[4];
  const float* W2  = (const float*)d_in[5];
  const float* b2  = (const float*)d_in[6];
  const int*   eidx= (const int*)d_in[7];

  const int IN = 256, H = 128, OUT = 64;
  const int n = in_sizes[0] / IN;   // 50000
  const int E = in_sizes[7] / 2;    // 800000
  const int L = in_sizes[4];        // 4

  size_t off = 0;
  auto carve = [&](size_t bytes) -> void* {
    void* p = (char*)d_ws + off;
    off += (bytes + 255) & ~(size_t)255;
    return p;
  };
  int*    degi     = (int*)carve((size_t)n * 4);
  int*    rowstart = (int*)carve((size_t)(n + 1) * 4);
  int*    cursor   = (int*)carve((size_t)n * 4);
  int*    bsum     = (int*)carve(64 * 4);
  int*    boff     = (int*)carve(64 * 4);
  void*   colidx   = carve((size_t)E * 4);   // ushort or int
  float*  dinv     = (float*)carve((size_t)n * 4);
  ushort* h0bf     = (ushort*)carve((size_t)n * H * 2);
  ushort* hbf      = (ushort*)carve((size_t)n * H * 2);
  ushort* pre      = (ushort*)carve((size_t)n * H * 2);
  ushort* wr_bf    = (ushort*)carve((size_t)L * H * H * 2);
  ushort* w1t      = (ushort*)carve((size_t)IN * H * 2);
  ushort* w2t      = (ushort*)carve((size_t)H * OUT * 2);
  if (off > ws_size) return;

  const bool small = (n < 65536);

  // ---- CSR build + weight convert ----
  hipMemsetAsync(degi, 0, (size_t)n * 4, stream);
  k_count<<<(E + 255) / 256, 256, 0, stream>>>(eidx, degi, E, n);
  int nwr = L * H * H, nw1 = IN * H, nw2 = H * OUT;
  k_cvt<<<(nwr + nw1 + nw2 + 255) / 256, 256, 0, stream>>>(Wr, W1, W2, wr_bf, w1t, w2t,
                                                           nwr, nw1, nw2);
  int nb = (n + 1023) / 1024;
  k_scan1<<<nb, 1024, 0, stream>>>(degi, rowstart, bsum, n);
  k_scan2<<<1, 64, 0, stream>>>(bsum, boff, nb);
  k_scan3<<<nb, 1024, 0, stream>>>(rowstart, boff, cursor, degi, dinv, n, E);
  if (small)
    k_fill<ushort><<<(E + 255) / 256, 256, 0, stream>>>(eidx, cursor, (ushort*)colidx, E, n);
  else
    k_fill<int><<<(E + 255) / 256, 256, 0, stream>>>(eidx, cursor, (int*)colidx, E, n);

  int gx32 = (n + 31) / 32;
  int nb4 = (n + 3) / 4;
  // ---- lin1 + relu -> hbf (bf16; layer-0 h0 aliases hbf) ----
  mfma_gemm<256, 128, 2, true, 0><<<gx32, 256, 0, stream>>>(x, w1t, b1, nullptr, hbf,
                                                            nullptr, n);
  // ---- layers ----
  for (int l = 0; l < L; ++l) {
    mfma_gemm<128, 128, 2, false, 1><<<gx32, 256, 0, stream>>>(
        hbf, wr_bf + (size_t)l * H * H, nullptr, dinv, pre, nullptr, n);
    const ushort* h0in = (l == 0) ? hbf : h0bf;
    if (small)
      k_spmm5<ushort><<<4 * nb4, 256, 0, stream>>>(pre, dinv, rowstart,
          (const ushort*)colidx, eps, l, h0in, h0bf, hbf, n);
    else
      k_spmm5<int><<<4 * nb4, 256, 0, stream>>>(pre, dinv, rowstart,
          (const int*)colidx, eps, l, h0in, h0bf, hbf, n);
  }
  // ---- lin2 -> out (fp32) ----
  mfma_gemm<128, 64, 2, false, 2><<<gx32, 256, 0, stream>>>(hbf, w2t, b2, nullptr, nullptr,
                                                            (float*)d_out, n);
}